// Round 1
// baseline (500.586 us; speedup 1.0000x reference)
//
#include <hip/hip_runtime.h>

#define TC 128
#define KD 64
#define WLOG_MIN (-5.2983174f)   // ln(0.005)

// ---------------------------------------------------------------------------
// K1: per-(b,h,chunk) block. Computes:
//   - exclusive cumsum "sh" of wlog = max(w, ln 0.005)
//   - ki   = k * exp(off - cum)        (LDS)
//   - vcs  = v                          (LDS)
//   - diag[t] = sum_k r*u*k
//   - out_intra = (tril(rd ki^T, -1) + diag I) @ v   -> d_out
//   - wkv_chunk[k][j] = wsoff[k] * sum_t ki[t][k] v[t][j] -> ws
//   - wse[k] = exp(ws_sum[k])                              -> ws
// ---------------------------------------------------------------------------
__global__ __launch_bounds__(256)
void rwkv_intra_kernel(const float* __restrict__ rr, const float* __restrict__ kk_,
                       const float* __restrict__ vv, const float* __restrict__ ww,
                       const float* __restrict__ uu, float* __restrict__ out,
                       float* __restrict__ wkv_ws, float* __restrict__ wse_ws,
                       int H, int N) {
  __shared__ float sh[TC][KD + 1];   // padded: conflict-free column-ish reads
  __shared__ float ki[TC][KD];
  __shared__ float vcs[TC][KD];
  __shared__ float segtot[4][KD];
  __shared__ float segoff[4][KD];
  __shared__ float offk[KD];
  __shared__ float wsoffs[KD];
  __shared__ float diag[TC];

  const int bid = blockIdx.x;
  const int n = bid % N;
  const int bh = bid / N;
  const int h = bh % H;
  const size_t base = ((size_t)bh * N + n) * (TC * KD);
  const float* rg = rr + base;
  const float* kg = kk_ + base;
  const float* vg = vv + base;
  const float* wg = ww + base;

  const int tid = threadIdx.x;
  const int lk = tid & 63;
  const int seg = tid >> 6;

  // ---- segmented exclusive cumsum over t (per k column) ----
  float c = 0.f;
  #pragma unroll
  for (int tt = 0; tt < 32; ++tt) {
    const int t = seg * 32 + tt;
    float wl = fmaxf(wg[t * KD + lk], WLOG_MIN);
    sh[t][lk] = c;
    c += wl;
  }
  segtot[seg][lk] = c;
  __syncthreads();
  if (tid < KD) {
    float s0 = segtot[0][tid], s1 = segtot[1][tid], s2 = segtot[2][tid], s3 = segtot[3][tid];
    segoff[0][tid] = 0.f; segoff[1][tid] = s0; segoff[2][tid] = s0 + s1; segoff[3][tid] = s0 + s1 + s2;
    float off = s0 + s1;             // shifted at t = Tc/2 (= start of seg 2)
    float wsum = s0 + s1 + s2 + s3;  // total chunk decay
    offk[tid] = off;
    wsoffs[tid] = __expf(wsum - off);
    wse_ws[((size_t)bh * N + n) * KD + tid] = __expf(wsum);
  }
  __syncthreads();
  {
    float so = segoff[seg][lk];
    #pragma unroll
    for (int tt = 0; tt < 32; ++tt) sh[seg * 32 + tt][lk] += so;
  }
  __syncthreads();

  // ---- transforms (ki, vcs) + diag reduction (wave covers a full row) ----
  {
    const float uk = uu[h * KD + lk];
    const float off = offk[lk];
    for (int it = 0; it < 32; ++it) {
      const int t = it * 4 + seg;  // wave-uniform t
      float s = sh[t][lk];
      float wl = fmaxf(wg[t * KD + lk], WLOG_MIN);
      float kraw = kg[t * KD + lk];
      ki[t][lk] = kraw * __expf(off - (s + wl));
      vcs[t][lk] = vg[t * KD + lk];
      float d = rg[t * KD + lk] * uk * kraw;
      #pragma unroll
      for (int o = 32; o > 0; o >>= 1) d += __shfl_xor(d, o, 64);
      if (lk == 0) diag[t] = d;
    }
  }
  __syncthreads();

  // ---- out_intra: thread = (row i, v-half) ----
  {
    const int i = tid & 127;
    const int vh = tid >> 7;
    float rdrow[KD];
    #pragma unroll
    for (int q = 0; q < KD; ++q)
      rdrow[q] = rg[i * KD + q] * __expf(sh[i][q] - offk[q]);
    const float dia = diag[i];
    float acc[32];
    #pragma unroll
    for (int q = 0; q < 32; ++q) acc[q] = 0.f;
    const int jmax = i | 63;  // wave-uniform upper bound (skip all-dead j's)
    for (int j = 0; j <= jmax; ++j) {
      const float4* kr = (const float4*)(&ki[j][0]);  // broadcast rows
      float a = 0.f;
      #pragma unroll
      for (int q = 0; q < 16; ++q) {
        float4 kv = kr[q];
        a += rdrow[4 * q] * kv.x + rdrow[4 * q + 1] * kv.y +
             rdrow[4 * q + 2] * kv.z + rdrow[4 * q + 3] * kv.w;
      }
      a = (j < i) ? a : ((j == i) ? dia : 0.f);
      const float4* vr = (const float4*)(&vcs[j][vh * 32]);
      #pragma unroll
      for (int q = 0; q < 8; ++q) {
        float4 v4 = vr[q];
        acc[4 * q]     += a * v4.x;
        acc[4 * q + 1] += a * v4.y;
        acc[4 * q + 2] += a * v4.z;
        acc[4 * q + 3] += a * v4.w;
      }
    }
    float* og = out + base + (size_t)i * KD + vh * 32;
    #pragma unroll
    for (int q = 0; q < 8; ++q)
      ((float4*)og)[q] = make_float4(acc[4 * q], acc[4 * q + 1], acc[4 * q + 2], acc[4 * q + 3]);
  }

  // ---- wkv chunk contribution (64x64), 16x16 thread grid, 4x4 tiles ----
  {
    const int k0 = (tid >> 4) << 2;
    const int j0 = (tid & 15) << 2;
    float wa[4][4];
    #pragma unroll
    for (int x = 0; x < 4; ++x)
      #pragma unroll
      for (int y = 0; y < 4; ++y) wa[x][y] = 0.f;
    for (int t = 0; t < TC; ++t) {
      float4 kv = *(const float4*)(&ki[t][k0]);
      float4 v4 = *(const float4*)(&vcs[t][j0]);
      float kx[4] = {kv.x, kv.y, kv.z, kv.w};
      float vx[4] = {v4.x, v4.y, v4.z, v4.w};
      #pragma unroll
      for (int x = 0; x < 4; ++x)
        #pragma unroll
        for (int y = 0; y < 4; ++y) wa[x][y] += kx[x] * vx[y];
    }
    float* wkvg = wkv_ws + ((size_t)bh * N + n) * (KD * KD);
    #pragma unroll
    for (int x = 0; x < 4; ++x) {
      float sc = wsoffs[k0 + x];
      *(float4*)(&wkvg[(k0 + x) * KD + j0]) =
          make_float4(sc * wa[x][0], sc * wa[x][1], sc * wa[x][2], sc * wa[x][3]);
    }
  }
}

// ---------------------------------------------------------------------------
// K2: per-(b,h) sequential scan over chunks. Emits pre-update states + final.
// ---------------------------------------------------------------------------
__global__ __launch_bounds__(256)
void rwkv_scan_kernel(const float* __restrict__ wkv_ws, const float* __restrict__ wse_ws,
                      const float* __restrict__ st_in, float* __restrict__ states_ws,
                      float* __restrict__ final_out, int N) {
  const int bh = blockIdx.x;
  const int tid = threadIdx.x;
  float stt[16];
  #pragma unroll
  for (int x = 0; x < 16; ++x) stt[x] = st_in[(size_t)bh * (KD * KD) + tid + x * 256];
  for (int nn = 0; nn < N; ++nn) {
    const float* wk = wkv_ws + ((size_t)bh * N + nn) * (KD * KD);
    const float* we = wse_ws + ((size_t)bh * N + nn) * KD;
    float* so = states_ws + ((size_t)bh * N + nn) * (KD * KD);
    #pragma unroll
    for (int x = 0; x < 16; ++x) {
      int idx = tid + x * 256;
      so[idx] = stt[x];                          // state BEFORE update (scan ys)
      stt[x] = stt[x] * we[idx >> 6] + wk[idx];  // row-k scale + wkv
    }
  }
  #pragma unroll
  for (int x = 0; x < 16; ++x) final_out[(size_t)bh * (KD * KD) + tid + x * 256] = stt[x];
}

// ---------------------------------------------------------------------------
// K3: per-(b,h,chunk) block: out += (r * exp(shifted)) @ state_n
// ---------------------------------------------------------------------------
__global__ __launch_bounds__(256)
void rwkv_inter_kernel(const float* __restrict__ rr, const float* __restrict__ ww,
                       const float* __restrict__ states_ws, float* __restrict__ out, int N) {
  __shared__ float sh[TC][KD + 1];
  __shared__ float st[KD][KD];
  __shared__ float segtot[4][KD];
  __shared__ float segoff[4][KD];
  const int bid = blockIdx.x;
  const int n = bid % N, bh = bid / N;
  const size_t base = ((size_t)bh * N + n) * (TC * KD);
  const float* rg = rr + base;
  const float* wg = ww + base;
  const int tid = threadIdx.x, lk = tid & 63, seg = tid >> 6;

  float c = 0.f;
  #pragma unroll
  for (int tt = 0; tt < 32; ++tt) {
    int t = seg * 32 + tt;
    float wl = fmaxf(wg[t * KD + lk], WLOG_MIN);
    sh[t][lk] = c;
    c += wl;
  }
  segtot[seg][lk] = c;
  const float* sg = states_ws + ((size_t)bh * N + n) * (KD * KD);
  #pragma unroll
  for (int x = 0; x < 16; ++x) { int idx = tid + x * 256; ((float*)st)[idx] = sg[idx]; }
  __syncthreads();
  if (tid < KD) {
    float s0 = segtot[0][tid], s1 = segtot[1][tid], s2 = segtot[2][tid];
    segoff[0][tid] = 0.f; segoff[1][tid] = s0; segoff[2][tid] = s0 + s1; segoff[3][tid] = s0 + s1 + s2;
  }
  __syncthreads();
  {
    float so = segoff[seg][lk];
    #pragma unroll
    for (int tt = 0; tt < 32; ++tt) sh[seg * 32 + tt][lk] += so;
  }
  __syncthreads();

  const int i = tid & 127, vh = tid >> 7;
  float acc[32];
  #pragma unroll
  for (int q = 0; q < 32; ++q) acc[q] = 0.f;
  for (int q = 0; q < KD; ++q) {
    float a = rg[i * KD + q] * __expf(sh[i][q]);
    const float4* srow = (const float4*)(&st[q][vh * 32]);
    #pragma unroll
    for (int x = 0; x < 8; ++x) {
      float4 s4 = srow[x];
      acc[4 * x]     += a * s4.x;
      acc[4 * x + 1] += a * s4.y;
      acc[4 * x + 2] += a * s4.z;
      acc[4 * x + 3] += a * s4.w;
    }
  }
  float* og = out + base + (size_t)i * KD + vh * 32;
  #pragma unroll
  for (int x = 0; x < 8; ++x) {
    float4 o4 = ((float4*)og)[x];
    o4.x += acc[4 * x]; o4.y += acc[4 * x + 1]; o4.z += acc[4 * x + 2]; o4.w += acc[4 * x + 3];
    ((float4*)og)[x] = o4;
  }
}

// ---------------------------------------------------------------------------
// Workspace layout (floats): [wkv: BH*N*K*K][wse: BH*N*K][states: BH*N*K*K]
// = (4194304 + 65536 + 4194304) * 4 B ~= 33.8 MB
// ---------------------------------------------------------------------------
extern "C" void kernel_launch(void* const* d_in, const int* in_sizes, int n_in,
                              void* d_out, int out_size, void* d_ws, size_t ws_size,
                              hipStream_t stream) {
  const float* r = (const float*)d_in[0];
  const float* k = (const float*)d_in[1];
  const float* v = (const float*)d_in[2];
  const float* w = (const float*)d_in[3];
  const float* u = (const float*)d_in[4];
  const float* st0 = (const float*)d_in[5];
  float* out = (float*)d_out;

  const int BH = in_sizes[5] / (KD * KD);  // 64
  const int H = in_sizes[4] / KD;          // 16
  const int T = in_sizes[0] / (BH * KD);   // 2048
  const int N = T / TC;                    // 16

  float* wkv_ws = (float*)d_ws;
  float* wse_ws = wkv_ws + (size_t)BH * N * KD * KD;
  float* states_ws = wse_ws + (size_t)BH * N * KD;
  float* final_out = out + (size_t)in_sizes[0];

  rwkv_intra_kernel<<<BH * N, 256, 0, stream>>>(r, k, v, w, u, out, wkv_ws, wse_ws, H, N);
  rwkv_scan_kernel<<<BH, 256, 0, stream>>>(wkv_ws, wse_ws, st0, states_ws, final_out, N);
  rwkv_inter_kernel<<<BH * N, 256, 0, stream>>>(r, w, states_ws, out, N);
}

// Round 2
// 289.113 us; speedup vs baseline: 1.7315x; 1.7315x over previous
//
#include <hip/hip_runtime.h>

#define TC 128
#define KD 64
#define WLOG_MIN (-5.2983174f)   // ln(0.005)

typedef __attribute__((ext_vector_type(8))) short short8;
typedef __attribute__((ext_vector_type(4))) float f32x4;

__device__ __forceinline__ unsigned short f2bf(float x) {
  union { float f; unsigned int u; } c; c.f = x;
  unsigned int u = c.u + 0x7fffu + ((c.u >> 16) & 1u);   // RNE
  return (unsigned short)(u >> 16);
}

// LDS swizzle: element (row, c) of a [R][C] bf16 array stored at
// row*C + ((((c>>3) ^ (row & 7)) << 3) | (c & 7)); 16B-chunk (group g) reads at
// row*C + ((g ^ (row&7)) << 3). Spreads MFMA fragment b128 reads across banks.

// ---------------------------------------------------------------------------
// K1: per-(b,h,chunk). Stages rd/ki (natural), kiT/vT (transposed) as bf16,
// then MFMA: wkv = kiT@v (scaled), A = rd@ki^T (masked tril-1 + diag),
// out = A@v. C/D layout: col=lane&15, row=quad*4+reg. A-op: m=lane&15,
// k=quad*8+j. B-op: n=lane&15, k=quad*8+j (B stored [n][k]-contiguous).
// ---------------------------------------------------------------------------
__global__ __launch_bounds__(256, 1)
void rwkv_intra_mfma(const float* __restrict__ rr, const float* __restrict__ kk_,
                     const float* __restrict__ vv, const float* __restrict__ ww,
                     const float* __restrict__ uu, float* __restrict__ out,
                     float* __restrict__ wkv_ws, float* __restrict__ wse_ws,
                     int H, int N) {
  __shared__ unsigned short rd_s[TC * KD];    // [t][kd] natural
  __shared__ unsigned short ki_s[TC * KD];    // [t][kd] natural
  __shared__ unsigned short kiT_s[KD * TC];   // [kd][t]
  __shared__ unsigned short vT_s[KD * TC];    // [vd][t]
  __shared__ unsigned short A_s[TC * TC];     // [i][j] masked scores, bf16
  __shared__ float diag[TC];
  __shared__ float offs[KD], wsoffs[KD];
  __shared__ float segtot[4][KD], segoff[4][KD];

  const int bid = blockIdx.x;
  const int n = bid % N, bh = bid / N, h = bh % H;
  const size_t base = ((size_t)bh * N + n) * (TC * KD);
  const float *rg = rr + base, *kg = kk_ + base, *vg = vv + base, *wg = ww + base;

  const int tid = threadIdx.x;
  const int lk = tid & 63;    // lane = k-column during staging
  const int wv = tid >> 6;    // wave id = t-segment

  // ---- pass 1: load w (kept in regs), segment totals ----
  float wl[32];
  {
    float c = 0.f;
    #pragma unroll
    for (int tt = 0; tt < 32; ++tt) {
      wl[tt] = fmaxf(wg[(wv * 32 + tt) * KD + lk], WLOG_MIN);
      c += wl[tt];
    }
    segtot[wv][lk] = c;
  }
  __syncthreads();
  if (tid < KD) {
    float s0 = segtot[0][tid], s1 = segtot[1][tid], s2 = segtot[2][tid], s3 = segtot[3][tid];
    segoff[0][tid] = 0.f; segoff[1][tid] = s0; segoff[2][tid] = s0 + s1; segoff[3][tid] = s0 + s1 + s2;
    float off = s0 + s1, wsum = s0 + s1 + s2 + s3;
    offs[tid] = off;
    wsoffs[tid] = __expf(wsum - off);
    wse_ws[((size_t)bh * N + n) * KD + tid] = __expf(wsum);
  }
  __syncthreads();

  // ---- pass 2: staging (exclusive cumsum in regs; emit bf16 arrays + diag) ----
  {
    float c = segoff[wv][lk];
    const float off = offs[lk];
    const float uk = uu[h * KD + lk];
    short8 kib8, vb8;
    #pragma unroll
    for (int tt = 0; tt < 32; ++tt) {
      const int t = wv * 32 + tt;
      float rv = rg[t * KD + lk], kv = kg[t * KD + lk], vvv = vg[t * KD + lk];
      const int nat = t * KD + ((((lk >> 3) ^ (t & 7)) << 3) | (lk & 7));
      rd_s[nat] = f2bf(rv * __expf(c - off));
      unsigned short kib = f2bf(kv * __expf(off - c - wl[tt]));
      ki_s[nat] = kib;
      kib8[tt & 7] = (short)kib;
      vb8[tt & 7] = (short)f2bf(vvv);
      float d = rv * uk * kv;
      #pragma unroll
      for (int o = 32; o > 0; o >>= 1) d += __shfl_xor(d, o, 64);
      if (lk == 0) diag[t] = d;
      c += wl[tt];
      if ((tt & 7) == 7) {
        const int g = t >> 3;  // chunk group in t
        *(short8*)&kiT_s[lk * TC + ((g ^ (lk & 7)) << 3)] = kib8;
        *(short8*)&vT_s [lk * TC + ((g ^ (lk & 7)) << 3)] = vb8;
      }
    }
  }
  __syncthreads();

  const int lane = tid & 63, quad = lane >> 4, l16 = lane & 15;

  // ---- wkv = (ki * w_inter)^T @ v : D[kd][vd], wave wv owns kd-block wv ----
  {
    f32x4 acc[4] = {{0,0,0,0},{0,0,0,0},{0,0,0,0},{0,0,0,0}};
    const int kd = wv * 16 + l16;
    #pragma unroll
    for (int ks = 0; ks < 4; ++ks) {
      const int g = ks * 4 + quad;
      short8 a = *(const short8*)&kiT_s[kd * TC + ((g ^ (kd & 7)) << 3)];
      #pragma unroll
      for (int nn = 0; nn < 4; ++nn) {
        const int vd = nn * 16 + l16;
        short8 b = *(const short8*)&vT_s[vd * TC + ((g ^ (vd & 7)) << 3)];
        acc[nn] = __builtin_amdgcn_mfma_f32_16x16x32_bf16(a, b, acc[nn], 0, 0, 0);
      }
    }
    float* wkvg = wkv_ws + ((size_t)bh * N + n) * (KD * KD);
    #pragma unroll
    for (int nn = 0; nn < 4; ++nn)
      #pragma unroll
      for (int reg = 0; reg < 4; ++reg) {
        const int kde = wv * 16 + quad * 4 + reg;
        wkvg[kde * KD + nn * 16 + l16] = acc[nn][reg] * wsoffs[kde];
      }
  }

  // ---- A = tril(rd @ ki^T, -1) + diag*I : waves cover i-block pairs (w,7-w) ----
  #pragma unroll
  for (int half = 0; half < 2; ++half) {
    const int ib = half ? (7 - wv) : wv;
    const int i0 = ib * 16;
    const int irow = i0 + l16;
    short8 a0 = *(const short8*)&rd_s[irow * KD + ((quad ^ (irow & 7)) << 3)];
    short8 a1 = *(const short8*)&rd_s[irow * KD + (((4 + quad) ^ (irow & 7)) << 3)];
    for (int j = 0; j <= ib; ++j) {
      const int jrow = j * 16 + l16;
      short8 b0 = *(const short8*)&ki_s[jrow * KD + ((quad ^ (jrow & 7)) << 3)];
      short8 b1 = *(const short8*)&ki_s[jrow * KD + (((4 + quad) ^ (jrow & 7)) << 3)];
      f32x4 acc = {0, 0, 0, 0};
      acc = __builtin_amdgcn_mfma_f32_16x16x32_bf16(a0, b0, acc, 0, 0, 0);
      acc = __builtin_amdgcn_mfma_f32_16x16x32_bf16(a1, b1, acc, 0, 0, 0);
      #pragma unroll
      for (int reg = 0; reg < 4; ++reg) {
        const int ie = i0 + quad * 4 + reg;
        const int je = j * 16 + l16;
        float val = acc[reg];
        if (j == ib) val = (je < ie) ? val : ((je == ie) ? diag[ie] : 0.f);
        A_s[ie * TC + ((((je >> 3) ^ (ie & 7)) << 3) | (je & 7))] = f2bf(val);
      }
    }
    if ((ib & 1) == 0) {  // zero guard tile (ib, ib+1): read by last k-step
      if (lane < 32) {
        const int ie = i0 + (lane & 15);
        const int g = ((i0 + 16) >> 3) + (lane >> 4);
        short8 z = 0;
        *(short8*)&A_s[ie * TC + ((g ^ (ie & 7)) << 3)] = z;
      }
    }
  }
  __syncthreads();

  // ---- out_intra = A @ v : waves cover i-block pairs (w,7-w), k-steps to diag ----
  #pragma unroll
  for (int half = 0; half < 2; ++half) {
    const int ib = half ? (7 - wv) : wv;
    const int i0 = ib * 16;
    const int irow = i0 + l16;
    const int nks = (ib + 2) >> 1;
    f32x4 acc[4] = {{0,0,0,0},{0,0,0,0},{0,0,0,0},{0,0,0,0}};
    for (int ks = 0; ks < nks; ++ks) {
      const int g = ks * 4 + quad;
      short8 a = *(const short8*)&A_s[irow * TC + ((g ^ (irow & 7)) << 3)];
      #pragma unroll
      for (int nn = 0; nn < 4; ++nn) {
        const int vd = nn * 16 + l16;
        short8 b = *(const short8*)&vT_s[vd * TC + ((g ^ (vd & 7)) << 3)];
        acc[nn] = __builtin_amdgcn_mfma_f32_16x16x32_bf16(a, b, acc[nn], 0, 0, 0);
      }
    }
    float* og = out + base;
    #pragma unroll
    for (int nn = 0; nn < 4; ++nn)
      #pragma unroll
      for (int reg = 0; reg < 4; ++reg) {
        const int ie = i0 + quad * 4 + reg;
        og[ie * KD + nn * 16 + l16] = acc[nn][reg];
      }
  }
}

// ---------------------------------------------------------------------------
// K2: sequential chunk scan; v-columns independent -> 4 blocks per (b,h).
// ---------------------------------------------------------------------------
__global__ __launch_bounds__(256)
void rwkv_scan_kernel(const float* __restrict__ wkv_ws, const float* __restrict__ wse_ws,
                      const float* __restrict__ st_in, float* __restrict__ states_ws,
                      float* __restrict__ final_out, int N) {
  const int bh = blockIdx.x >> 2;
  const int vq = blockIdx.x & 3;
  const int tid = threadIdx.x;
  const size_t sbase = (size_t)bh * (KD * KD);
  float stt[4];
  #pragma unroll
  for (int i = 0; i < 4; ++i) {
    int e = tid + i * 256;
    stt[i] = st_in[sbase + (e >> 4) * KD + vq * 16 + (e & 15)];
  }
  for (int nn = 0; nn < N; ++nn) {
    const float* wk = wkv_ws + ((size_t)bh * N + nn) * (KD * KD);
    const float* we = wse_ws + ((size_t)bh * N + nn) * KD;
    float* so = states_ws + ((size_t)bh * N + nn) * (KD * KD);
    #pragma unroll
    for (int i = 0; i < 4; ++i) {
      int e = tid + i * 256;
      int idx = (e >> 4) * KD + vq * 16 + (e & 15);
      so[idx] = stt[i];                        // pre-update state (scan output)
      stt[i] = stt[i] * we[e >> 4] + wk[idx];
    }
  }
  #pragma unroll
  for (int i = 0; i < 4; ++i) {
    int e = tid + i * 256;
    final_out[sbase + (e >> 4) * KD + vq * 16 + (e & 15)] = stt[i];
  }
}

// ---------------------------------------------------------------------------
// K3: out += (r * exp(shifted)) @ state_n  via MFMA. ~26KB LDS.
// ---------------------------------------------------------------------------
__global__ __launch_bounds__(256, 1)
void rwkv_inter_mfma(const float* __restrict__ rr, const float* __restrict__ ww,
                     const float* __restrict__ states_ws, float* __restrict__ out, int N) {
  __shared__ unsigned short rw_s[TC * KD];    // [t][kd]
  __shared__ unsigned short stT_s[KD * KD];   // [vd][kd]
  __shared__ float segtot[4][KD], segoff[4][KD];
  const int bid = blockIdx.x;
  const int n = bid % N, bh = bid / N;
  const size_t base = ((size_t)bh * N + n) * (TC * KD);
  const float *rg = rr + base, *wg = ww + base;
  const int tid = threadIdx.x, lk = tid & 63, wv = tid >> 6;

  float wl[32];
  {
    float c = 0.f;
    #pragma unroll
    for (int tt = 0; tt < 32; ++tt) {
      wl[tt] = fmaxf(wg[(wv * 32 + tt) * KD + lk], WLOG_MIN);
      c += wl[tt];
    }
    segtot[wv][lk] = c;
  }
  // stage state^T (coalesced read, swizzled transposed LDS write)
  {
    const float* sg = states_ws + ((size_t)bh * N + n) * (KD * KD);
    #pragma unroll
    for (int x = 0; x < 16; ++x) {
      int idx = tid + x * 256;
      int kd = idx >> 6, vd = idx & 63;
      stT_s[vd * KD + ((((kd >> 3) ^ (vd & 7)) << 3) | (kd & 7))] = f2bf(sg[idx]);
    }
  }
  __syncthreads();
  if (tid < KD) {
    float s0 = segtot[0][tid], s1 = segtot[1][tid], s2 = segtot[2][tid];
    segoff[0][tid] = 0.f; segoff[1][tid] = s0; segoff[2][tid] = s0 + s1; segoff[3][tid] = s0 + s1 + s2;
  }
  __syncthreads();
  {
    float c = segoff[wv][lk];
    #pragma unroll
    for (int tt = 0; tt < 32; ++tt) {
      const int t = wv * 32 + tt;
      rw_s[t * KD + ((((lk >> 3) ^ (t & 7)) << 3) | (lk & 7))] = f2bf(rg[t * KD + lk] * __expf(c));
      c += wl[tt];
    }
  }
  __syncthreads();

  const int lane = tid & 63, quad = lane >> 4, l16 = lane & 15;
  #pragma unroll
  for (int half = 0; half < 2; ++half) {
    const int ib = wv + half * 4;
    const int i0 = ib * 16;
    const int irow = i0 + l16;
    short8 a0 = *(const short8*)&rw_s[irow * KD + ((quad ^ (irow & 7)) << 3)];
    short8 a1 = *(const short8*)&rw_s[irow * KD + (((4 + quad) ^ (irow & 7)) << 3)];
    f32x4 acc[4] = {{0,0,0,0},{0,0,0,0},{0,0,0,0},{0,0,0,0}};
    #pragma unroll
    for (int nn = 0; nn < 4; ++nn) {
      const int vd = nn * 16 + l16;
      short8 b0 = *(const short8*)&stT_s[vd * KD + ((quad ^ (vd & 7)) << 3)];
      short8 b1 = *(const short8*)&stT_s[vd * KD + (((4 + quad) ^ (vd & 7)) << 3)];
      acc[nn] = __builtin_amdgcn_mfma_f32_16x16x32_bf16(a0, b0, acc[nn], 0, 0, 0);
      acc[nn] = __builtin_amdgcn_mfma_f32_16x16x32_bf16(a1, b1, acc[nn], 0, 0, 0);
    }
    float* og = out + base;
    #pragma unroll
    for (int nn = 0; nn < 4; ++nn)
      #pragma unroll
      for (int reg = 0; reg < 4; ++reg) {
        const int ie = i0 + quad * 4 + reg;
        og[ie * KD + nn * 16 + l16] += acc[nn][reg];
      }
  }
}

// ---------------------------------------------------------------------------
// Workspace: [wkv: BH*N*K*K][wse: BH*N*K][states: BH*N*K*K] fp32 ~= 33.8 MB
// ---------------------------------------------------------------------------
extern "C" void kernel_launch(void* const* d_in, const int* in_sizes, int n_in,
                              void* d_out, int out_size, void* d_ws, size_t ws_size,
                              hipStream_t stream) {
  const float* r = (const float*)d_in[0];
  const float* k = (const float*)d_in[1];
  const float* v = (const float*)d_in[2];
  const float* w = (const float*)d_in[3];
  const float* u = (const float*)d_in[4];
  const float* st0 = (const float*)d_in[5];
  float* out = (float*)d_out;

  const int BH = in_sizes[5] / (KD * KD);  // 64
  const int H = in_sizes[4] / KD;          // 16
  const int T = in_sizes[0] / (BH * KD);   // 2048
  const int N = T / TC;                    // 16

  float* wkv_ws = (float*)d_ws;
  float* wse_ws = wkv_ws + (size_t)BH * N * KD * KD;
  float* states_ws = wse_ws + (size_t)BH * N * KD;
  float* final_out = out + (size_t)in_sizes[0];

  rwkv_intra_mfma<<<BH * N, 256, 0, stream>>>(r, k, v, w, u, out, wkv_ws, wse_ws, H, N);
  rwkv_scan_kernel<<<BH * 4, 256, 0, stream>>>(wkv_ws, wse_ws, st0, states_ws, final_out, N);
  rwkv_inter_mfma<<<BH * N, 256, 0, stream>>>(r, w, states_ws, out, N);
}

// Round 3
// 220.778 us; speedup vs baseline: 2.2674x; 1.3095x over previous
//
#include <hip/hip_runtime.h>

#define TC 128
#define KD 64
#define WLOG_MIN (-5.2983174f)   // ln(0.005)

typedef __attribute__((ext_vector_type(8))) short short8;
typedef __attribute__((ext_vector_type(4))) short short4_t;
typedef __attribute__((ext_vector_type(4))) float f32x4;

__device__ __forceinline__ unsigned short f2bf(float x) {
  union { float f; unsigned int u; } c; c.f = x;
  unsigned int u = c.u + 0x7fffu + ((c.u >> 16) & 1u);   // RNE
  return (unsigned short)(u >> 16);
}
__device__ __forceinline__ float bf2f(unsigned short x) {
  union { unsigned int u; float f; } c; c.u = ((unsigned int)x) << 16; return c.f;
}

// Natural-layout swizzle: element (row, c) of [R][64] bf16 stored at
// row*64 + ((((c>>3) ^ (row&7)) << 3) | (c&7)); 16B granule g read at
// row*64 + ((g ^ (row&7)) << 3). Transposed [64][128] arrays: granule g=t>>3
// at row*128 + ((g ^ (row&7)) << 3).

// ---------------------------------------------------------------------------
// K1: per-(b,h,chunk). 71KB LDS -> 2 blocks/CU. Phases:
//  pass1: w cumsum segment totals. pass2: stage rd/ki (natural), kiT/vT
//  (transposed) bf16 + diag + rw (bf16 -> ws for K3). Then (one sync):
//  wkv = kiT@v -> bf16 ws;  fused per-wave: Atile^T = ki@rd^T (2 MFMA),
//  mask, 8B repack into per-wave staging, out-MFMA against vT. No A matrix.
// ---------------------------------------------------------------------------
__global__ __launch_bounds__(256, 2)
void rwkv_intra_mfma(const float* __restrict__ rr, const float* __restrict__ kk_,
                     const float* __restrict__ vv, const float* __restrict__ ww,
                     const float* __restrict__ uu, float* __restrict__ out,
                     unsigned short* __restrict__ wkv_u16, float* __restrict__ wse_ws,
                     unsigned short* __restrict__ rw_u16, int H, int N) {
  __shared__ alignas(16) unsigned short rd_s[TC * KD];    // [t][kd] natural swz
  __shared__ alignas(16) unsigned short ki_s[TC * KD];    // [t][kd] natural swz
  __shared__ alignas(16) unsigned short kiT_s[KD * TC];   // [kd][t] swz
  __shared__ alignas(16) unsigned short vT_s[KD * TC];    // [vd][t] swz
  __shared__ alignas(16) unsigned short Ast[4][16 * 40];  // per-wave A staging (80B rows)
  __shared__ float diag[TC];
  __shared__ float segtot[4][KD];
  __shared__ float wsoffs[KD];

  const int bid = blockIdx.x;
  const int n = bid % N, bh = bid / N, h = bh % H;
  const size_t base = ((size_t)bh * N + n) * (TC * KD);
  const float *rg = rr + base, *kg = kk_ + base, *vg = vv + base, *wg = ww + base;

  const int tid = threadIdx.x;
  const int lk = tid & 63;    // k-column during staging
  const int wv = tid >> 6;    // wave id = t-segment

  // ---- pass 1: w (regs) + segment totals ----
  float wl[32];
  {
    float c = 0.f;
    #pragma unroll
    for (int tt = 0; tt < 32; ++tt) {
      wl[tt] = fmaxf(wg[(wv * 32 + tt) * KD + lk], WLOG_MIN);
      c += wl[tt];
    }
    segtot[wv][lk] = c;
  }
  __syncthreads();
  const float s0 = segtot[0][lk], s1 = segtot[1][lk], s2 = segtot[2][lk], s3 = segtot[3][lk];
  const float myoff = s0 + s1;   // cum at t = Tc/2
  const float segofs = (wv == 0) ? 0.f : (wv == 1) ? s0 : (wv == 2) ? (s0 + s1) : (s0 + s1 + s2);
  if (wv == 0) {
    const float wsum = s0 + s1 + s2 + s3;
    wsoffs[lk] = __expf(wsum - myoff);
    wse_ws[((size_t)bh * N + n) * KD + lk] = __expf(wsum);
  }
  const float eoff = __expf(myoff);

  // ---- pass 2: staging ----
  {
    float c = segofs;
    const float uk = uu[h * KD + lk];
    unsigned short* rwg = rw_u16 + base;
    short8 kib8, vb8;
    #pragma unroll
    for (int tt = 0; tt < 32; ++tt) {
      const int t = wv * 32 + tt;
      float rv = rg[t * KD + lk], kv = kg[t * KD + lk], vvv = vg[t * KD + lk];
      const int nat = t * KD + ((((lk >> 3) ^ (t & 7)) << 3) | (lk & 7));
      float e1 = __expf(c - myoff);
      rd_s[nat] = f2bf(rv * e1);
      rwg[t * KD + lk] = f2bf(rv * e1 * eoff);  // r * exp(cum) for K3
      unsigned short kib = f2bf(kv * __expf(myoff - c - wl[tt]));
      ki_s[nat] = kib;
      kib8[tt & 7] = (short)kib;
      vb8[tt & 7] = (short)f2bf(vvv);
      float d = rv * uk * kv;
      #pragma unroll
      for (int o = 32; o > 0; o >>= 1) d += __shfl_xor(d, o, 64);
      if (lk == 0) diag[t] = d;
      c += wl[tt];
      if ((tt & 7) == 7) {
        const int g = t >> 3;
        *(short8*)&kiT_s[lk * TC + ((g ^ (lk & 7)) << 3)] = kib8;
        *(short8*)&vT_s [lk * TC + ((g ^ (lk & 7)) << 3)] = vb8;
      }
    }
  }
  __syncthreads();

  const int lane = tid & 63, quad = lane >> 4, l16 = lane & 15;

  // ---- wkv = (ki * w_inter)^T @ v -> bf16 ws ----
  {
    f32x4 acc[4] = {{0,0,0,0},{0,0,0,0},{0,0,0,0},{0,0,0,0}};
    const int kd = wv * 16 + l16;
    #pragma unroll
    for (int ks = 0; ks < 4; ++ks) {
      const int g = ks * 4 + quad;
      short8 a = *(const short8*)&kiT_s[kd * TC + ((g ^ (kd & 7)) << 3)];
      #pragma unroll
      for (int nn = 0; nn < 4; ++nn) {
        const int vd = nn * 16 + l16;
        short8 b = *(const short8*)&vT_s[vd * TC + ((g ^ (vd & 7)) << 3)];
        acc[nn] = __builtin_amdgcn_mfma_f32_16x16x32_bf16(a, b, acc[nn], 0, 0, 0);
      }
    }
    unsigned short* wkvg = wkv_u16 + ((size_t)bh * N + n) * (KD * KD);
    #pragma unroll
    for (int nn = 0; nn < 4; ++nn)
      #pragma unroll
      for (int reg = 0; reg < 4; ++reg) {
        const int kde = wv * 16 + quad * 4 + reg;
        wkvg[kde * KD + nn * 16 + l16] = f2bf(acc[nn][reg] * wsoffs[kde]);
      }
  }

  // ---- fused A^T tiles + out = A@v (per-wave, no block sync) ----
  #pragma unroll
  for (int half = 0; half < 2; ++half) {
    const int ib = half ? (7 - wv) : wv;
    const int i0 = ib * 16;
    const int irow = i0 + l16;
    // B-operand (n = i) fragments from rd
    short8 b0 = *(const short8*)&rd_s[irow * KD + ((quad ^ (irow & 7)) << 3)];
    short8 b1 = *(const short8*)&rd_s[irow * KD + (((4 + quad) ^ (irow & 7)) << 3)];
    const float diag_i = diag[irow];
    f32x4 oacc[4] = {{0,0,0,0},{0,0,0,0},{0,0,0,0},{0,0,0,0}};
    const int npairs = (ib + 2) >> 1;
    unsigned short* astw = &Ast[wv][0];
    for (int jp = 0; jp < npairs; ++jp) {
      #pragma unroll
      for (int jj = 0; jj < 2; ++jj) {
        const int j = jp * 2 + jj;
        short4_t pk;
        if (j <= ib) {
          const int jrow = j * 16 + l16;
          // A-operand (m = j) fragments from ki -> D[j_local][i_local] = A^T
          short8 a0 = *(const short8*)&ki_s[jrow * KD + ((quad ^ (jrow & 7)) << 3)];
          short8 a1 = *(const short8*)&ki_s[jrow * KD + (((4 + quad) ^ (jrow & 7)) << 3)];
          f32x4 at = {0, 0, 0, 0};
          at = __builtin_amdgcn_mfma_f32_16x16x32_bf16(a0, b0, at, 0, 0, 0);
          at = __builtin_amdgcn_mfma_f32_16x16x32_bf16(a1, b1, at, 0, 0, 0);
          #pragma unroll
          for (int reg = 0; reg < 4; ++reg) {
            const int je = j * 16 + quad * 4 + reg;
            float val = at[reg];
            if (j == ib) val = (je < irow) ? val : ((je == irow) ? diag_i : 0.f);
            pk[reg] = (short)f2bf(val);
          }
        } else {
          pk = (short4_t)0;  // guard half for even ib
        }
        // element (ie=irow, je) -> row l16, col jj*16 + quad*4 (+reg); 8B write
        *(short4_t*)&astw[l16 * 40 + jj * 16 + quad * 4] = pk;
      }
      // A-op fragment: row l16, k-window jp*32 + quad*8 .. +7 (in-order LDS,
      // wave-private buffer -> no barrier needed)
      short8 af = *(const short8*)&astw[l16 * 40 + quad * 8];
      #pragma unroll
      for (int nn = 0; nn < 4; ++nn) {
        const int vd = nn * 16 + l16;
        const int g = jp * 4 + quad;
        short8 bv = *(const short8*)&vT_s[vd * TC + ((g ^ (vd & 7)) << 3)];
        oacc[nn] = __builtin_amdgcn_mfma_f32_16x16x32_bf16(af, bv, oacc[nn], 0, 0, 0);
      }
    }
    float* og = out + base;
    #pragma unroll
    for (int nn = 0; nn < 4; ++nn)
      #pragma unroll
      for (int reg = 0; reg < 4; ++reg) {
        const int ie = i0 + quad * 4 + reg;
        og[ie * KD + nn * 16 + l16] = oacc[nn][reg];
      }
  }
}

// ---------------------------------------------------------------------------
// K2: sequential chunk scan, software-pipelined loads; emits pre-update
// states as bf16, transposed+swizzled (K3 copies verbatim into LDS).
// ---------------------------------------------------------------------------
__global__ __launch_bounds__(256)
void rwkv_scan_kernel(const unsigned short* __restrict__ wkv_u16,
                      const float* __restrict__ wse_ws,
                      const float* __restrict__ st_in,
                      unsigned short* __restrict__ statesT_u16,
                      float* __restrict__ final_out, int N) {
  const int bh = blockIdx.x >> 2;
  const int vq = blockIdx.x & 3;
  const int tid = threadIdx.x;
  const size_t sbase = (size_t)bh * (KD * KD);
  float stt[4];
  int kd[4], vd[4], swz[4];
  #pragma unroll
  for (int i = 0; i < 4; ++i) {
    int e = tid + i * 256;
    kd[i] = e >> 4; vd[i] = vq * 16 + (e & 15);
    swz[i] = vd[i] * KD + ((((kd[i] >> 3) ^ (vd[i] & 7)) << 3) | (kd[i] & 7));
    stt[i] = st_in[sbase + kd[i] * KD + vd[i]];
  }
  float nwk[4], nwe[4];
  #pragma unroll
  for (int i = 0; i < 4; ++i) {
    nwk[i] = bf2f(wkv_u16[(size_t)bh * N * (KD * KD) + kd[i] * KD + vd[i]]);
    nwe[i] = wse_ws[(size_t)bh * N * KD + kd[i]];
  }
  for (int nn = 0; nn < N; ++nn) {
    float cwk[4], cwe[4];
    #pragma unroll
    for (int i = 0; i < 4; ++i) { cwk[i] = nwk[i]; cwe[i] = nwe[i]; }
    if (nn + 1 < N) {
      const size_t b2 = (size_t)bh * N + nn + 1;
      #pragma unroll
      for (int i = 0; i < 4; ++i) {
        nwk[i] = bf2f(wkv_u16[b2 * (KD * KD) + kd[i] * KD + vd[i]]);
        nwe[i] = wse_ws[b2 * KD + kd[i]];
      }
    }
    unsigned short* so = statesT_u16 + ((size_t)bh * N + nn) * (KD * KD);
    #pragma unroll
    for (int i = 0; i < 4; ++i) {
      so[swz[i]] = f2bf(stt[i]);               // pre-update state
      stt[i] = stt[i] * cwe[i] + cwk[i];
    }
  }
  #pragma unroll
  for (int i = 0; i < 4; ++i)
    final_out[sbase + kd[i] * KD + vd[i]] = stt[i];
}

// ---------------------------------------------------------------------------
// K3: out += rw @ state_n. Pure bf16 MFMA; 24KB LDS -> 6 blocks/CU.
// ---------------------------------------------------------------------------
__global__ __launch_bounds__(256)
void rwkv_inter_mfma(const unsigned short* __restrict__ rw_u16,
                     const unsigned short* __restrict__ statesT_u16,
                     float* __restrict__ out, int N) {
  __shared__ alignas(16) unsigned short rw_s[TC * KD];
  __shared__ alignas(16) unsigned short stT_s[KD * KD];
  const int bid = blockIdx.x;
  const int n = bid % N, bh = bid / N;
  const size_t base = ((size_t)bh * N + n) * (TC * KD);
  const int tid = threadIdx.x;
  {
    const short8* rwg = (const short8*)(rw_u16 + base);
    #pragma unroll
    for (int x = 0; x < 4; ++x) {
      int m = tid + x * 256;
      int t = m >> 3, g = m & 7;
      *(short8*)&rw_s[t * KD + ((g ^ (t & 7)) << 3)] = rwg[m];
    }
    const short8* sg = (const short8*)(statesT_u16 + ((size_t)bh * N + n) * (KD * KD));
    #pragma unroll
    for (int x = 0; x < 2; ++x) {
      int m = tid + x * 256;
      *(short8*)&stT_s[m * 8] = sg[m];   // already transposed+swizzled
    }
  }
  __syncthreads();
  const int lane = tid & 63, quad = lane >> 4, l16 = lane & 15, wv = tid >> 6;
  #pragma unroll
  for (int half = 0; half < 2; ++half) {
    const int ib = wv + half * 4;
    const int i0 = ib * 16, irow = i0 + l16;
    short8 a0 = *(const short8*)&rw_s[irow * KD + ((quad ^ (irow & 7)) << 3)];
    short8 a1 = *(const short8*)&rw_s[irow * KD + (((4 + quad) ^ (irow & 7)) << 3)];
    f32x4 acc[4] = {{0,0,0,0},{0,0,0,0},{0,0,0,0},{0,0,0,0}};
    #pragma unroll
    for (int nn = 0; nn < 4; ++nn) {
      const int vd = nn * 16 + l16;
      short8 bb0 = *(const short8*)&stT_s[vd * KD + ((quad ^ (vd & 7)) << 3)];
      short8 bb1 = *(const short8*)&stT_s[vd * KD + (((4 + quad) ^ (vd & 7)) << 3)];
      acc[nn] = __builtin_amdgcn_mfma_f32_16x16x32_bf16(a0, bb0, acc[nn], 0, 0, 0);
      acc[nn] = __builtin_amdgcn_mfma_f32_16x16x32_bf16(a1, bb1, acc[nn], 0, 0, 0);
    }
    float* og = out + base;
    #pragma unroll
    for (int nn = 0; nn < 4; ++nn)
      #pragma unroll
      for (int reg = 0; reg < 4; ++reg) {
        const int ie = i0 + quad * 4 + reg;
        og[ie * KD + nn * 16 + l16] += acc[nn][reg];
      }
  }
}

// ---------------------------------------------------------------------------
// Workspace (32.25 MB): [wkv u16: BH*N*K*K][wse f32: BH*N*K]
//                       [statesT u16: BH*N*K*K][rw u16: BH*T*K]
// ---------------------------------------------------------------------------
extern "C" void kernel_launch(void* const* d_in, const int* in_sizes, int n_in,
                              void* d_out, int out_size, void* d_ws, size_t ws_size,
                              hipStream_t stream) {
  const float* r = (const float*)d_in[0];
  const float* k = (const float*)d_in[1];
  const float* v = (const float*)d_in[2];
  const float* w = (const float*)d_in[3];
  const float* u = (const float*)d_in[4];
  const float* st0 = (const float*)d_in[5];
  float* out = (float*)d_out;

  const int BH = in_sizes[5] / (KD * KD);  // 64
  const int H = in_sizes[4] / KD;          // 16
  const int T = in_sizes[0] / (BH * KD);   // 2048
  const int N = T / TC;                    // 16

  unsigned short* wkv_u16 = (unsigned short*)d_ws;
  float* wse_ws = (float*)(wkv_u16 + (size_t)BH * N * KD * KD);
  unsigned short* statesT_u16 = (unsigned short*)(wse_ws + (size_t)BH * N * KD);
  unsigned short* rw_u16 = statesT_u16 + (size_t)BH * N * KD * KD;
  float* final_out = out + (size_t)in_sizes[0];

  rwkv_intra_mfma<<<BH * N, 256, 0, stream>>>(r, k, v, w, u, out, wkv_u16, wse_ws, rw_u16, H, N);
  rwkv_scan_kernel<<<BH * 4, 256, 0, stream>>>(wkv_u16, wse_ws, st0, statesT_u16, final_out, N);
  rwkv_inter_mfma<<<BH * N, 256, 0, stream>>>(rw_u16, statesT_u16, out, N);
}

// Round 4
// 205.198 us; speedup vs baseline: 2.4395x; 1.0759x over previous
//
#include <hip/hip_runtime.h>

#define TC 128
#define KD 64
#define WLOG_MIN (-5.2983174f)   // ln(0.005)

typedef __attribute__((ext_vector_type(8))) short short8;
typedef __attribute__((ext_vector_type(4))) short short4_t;
typedef __attribute__((ext_vector_type(4))) float f32x4;

__device__ __forceinline__ unsigned short f2bf(float x) {
  union { float f; unsigned int u; } c; c.f = x;
  unsigned int u = c.u + 0x7fffu + ((c.u >> 16) & 1u);   // RNE
  return (unsigned short)(u >> 16);
}
__device__ __forceinline__ float bf2f(unsigned short x) {
  union { unsigned int u; float f; } c; c.u = ((unsigned int)x) << 16; return c.f;
}

// rd_s/ki_s swizzle: element (t,kd) stored at t*64 + (slot<<3 | kd&7),
// slot = (kd>>3) ^ (t&7) ^ ((t>>3)&7).  b128 granule-q reads use
// slot = q ^ (t&7) ^ ((t>>3)&7).  vT/sT swizzle: slot = g ^ (row&7).

// ---------------------------------------------------------------------------
// K1: per-(b,h,chunk). 54,272B LDS -> 3 blocks/CU. Two barriers.
//  pass1: w cumsum seg totals (segtot, unioned with Ast).
//  pass2: stage rd/ki (natural swz) + vT (transposed swz) bf16; export
//         rw=r*exp(cum) bf16 + diag bf16 (global scratch) + wse.
//  post-barrier (per-wave, no sync): wkv = kiT@v (A-frags via scalar LDS
//  reads from natural ki) -> bf16 ws; fused A^T-tile -> mask -> per-wave
//  LDS repack -> out = A@v.
// ---------------------------------------------------------------------------
__global__ __launch_bounds__(256, 3)
void rwkv_intra_mfma(const float* __restrict__ rr, const float* __restrict__ kk_,
                     const float* __restrict__ vv, const float* __restrict__ ww,
                     const float* __restrict__ uu, float* __restrict__ out,
                     unsigned short* __restrict__ wkv_u16, float* __restrict__ wse_ws,
                     unsigned short* __restrict__ rw_u16, unsigned short* __restrict__ diag_u16,
                     int H, int N) {
  __shared__ alignas(16) unsigned short rd_s[TC * KD];
  __shared__ alignas(16) unsigned short ki_s[TC * KD];
  __shared__ alignas(16) unsigned short vT_s[KD * TC];
  __shared__ alignas(16) unsigned char su_raw[5120];   // union: segtot f32[4][64] | Ast u16[4][640]
  float* segtot = (float*)su_raw;
  unsigned short* Ast = (unsigned short*)su_raw;

  const int bid = blockIdx.x;
  const int n = bid % N, bh = bid / N, h = bh % H;
  const size_t base = ((size_t)bh * N + n) * (TC * KD);
  const float *rg = rr + base, *kg = kk_ + base, *vg = vv + base, *wg = ww + base;
  unsigned short* diagg = diag_u16 + (size_t)bid * TC;

  const int tid = threadIdx.x;
  const int lk = tid & 63;    // k-column during staging
  const int wv = tid >> 6;    // wave id = t-segment

  // ---- pass 1: w (regs) + segment totals ----
  float wl[32];
  {
    float c = 0.f;
    #pragma unroll
    for (int tt = 0; tt < 32; ++tt) {
      wl[tt] = fmaxf(wg[(wv * 32 + tt) * KD + lk], WLOG_MIN);
      c += wl[tt];
    }
    segtot[wv * 64 + lk] = c;
  }
  __syncthreads();
  const float s0 = segtot[0 * 64 + lk], s1 = segtot[1 * 64 + lk];
  const float s2 = segtot[2 * 64 + lk], s3 = segtot[3 * 64 + lk];
  const float myoff = s0 + s1;   // cum at t = Tc/2
  const float segofs = (wv == 0) ? 0.f : (wv == 1) ? s0 : (wv == 2) ? (s0 + s1) : (s0 + s1 + s2);
  const float wsum = s0 + s1 + s2 + s3;
  const float wsoff_own = __expf(wsum - myoff);   // kept in reg (segtot gets clobbered by Ast)
  if (wv == 0) wse_ws[((size_t)bh * N + n) * KD + lk] = __expf(wsum);
  const float eoff = __expf(myoff);

  // ---- pass 2: staging ----
  {
    float c = segofs;
    const float uk = uu[h * KD + lk];
    unsigned short* rwg = rw_u16 + base;
    short8 vb8;
    float darr[8];
    #pragma unroll
    for (int tt = 0; tt < 32; ++tt) {
      const int t = wv * 32 + tt;
      float rv = rg[t * KD + lk], kv = kg[t * KD + lk], vvv = vg[t * KD + lk];
      const int slot = (lk >> 3) ^ (t & 7) ^ ((t >> 3) & 7);
      const int nat = t * KD + (slot << 3) + (lk & 7);
      float e1 = __expf(c - myoff);
      rd_s[nat] = f2bf(rv * e1);
      rwg[t * KD + lk] = f2bf(rv * e1 * eoff);  // r * exp(cum) for scan_inter
      ki_s[nat] = f2bf(kv * __expf(myoff - c - wl[tt]));
      vb8[tt & 7] = (short)f2bf(vvv);
      darr[tt & 7] = rv * uk * kv;
      c += wl[tt];
      if ((tt & 7) == 7) {
        const int g = t >> 3;
        *(short8*)&vT_s[lk * TC + ((g ^ (lk & 7)) << 3)] = vb8;
        // batched butterfly: 8 independent reductions
        #pragma unroll
        for (int o = 32; o > 0; o >>= 1)
          #pragma unroll
          for (int q = 0; q < 8; ++q) darr[q] += __shfl_xor(darr[q], o, 64);
        if (lk == 0) {
          short8 dpk;
          #pragma unroll
          for (int q = 0; q < 8; ++q) dpk[q] = (short)f2bf(darr[q]);
          *(short8*)&diagg[g * 8] = dpk;
        }
      }
    }
  }
  __syncthreads();

  const int lane = tid & 63, quad = lane >> 4, l16 = lane & 15;

  // ---- wkv = (ki * w_inter)^T @ v -> bf16 ws (A-frags via scalar LDS reads) ----
  {
    f32x4 acc[4] = {{0,0,0,0},{0,0,0,0},{0,0,0,0},{0,0,0,0}};
    const int kdg = wv * 2 + (l16 >> 3), kd7 = l16 & 7;
    #pragma unroll
    for (int ks = 0; ks < 4; ++ks) {
      short8 a;
      #pragma unroll
      for (int j = 0; j < 8; ++j) {
        const int t = ks * 32 + quad * 8 + j;
        a[j] = (short)ki_s[t * KD + (((kdg ^ (t & 7) ^ ((t >> 3) & 7)) << 3) + kd7)];
      }
      #pragma unroll
      for (int nn = 0; nn < 4; ++nn) {
        const int vd = nn * 16 + l16;
        short8 b = *(const short8*)&vT_s[vd * TC + (((ks * 4 + quad) ^ (vd & 7)) << 3)];
        acc[nn] = __builtin_amdgcn_mfma_f32_16x16x32_bf16(a, b, acc[nn], 0, 0, 0);
      }
    }
    float wso[4];
    #pragma unroll
    for (int reg = 0; reg < 4; ++reg) wso[reg] = __shfl(wsoff_own, wv * 16 + quad * 4 + reg, 64);
    unsigned short* wkvg = wkv_u16 + ((size_t)bh * N + n) * (KD * KD);
    #pragma unroll
    for (int nn = 0; nn < 4; ++nn)
      #pragma unroll
      for (int reg = 0; reg < 4; ++reg)
        wkvg[(wv * 16 + quad * 4 + reg) * KD + nn * 16 + l16] = f2bf(acc[nn][reg] * wso[reg]);
  }

  // ---- fused A^T tiles + out = A@v (per-wave, no block sync) ----
  #pragma unroll
  for (int half = 0; half < 2; ++half) {
    const int ib = half ? (7 - wv) : wv;
    const int i0 = ib * 16;
    const int irow = i0 + l16;
    const int rsw = (irow & 7) ^ ((irow >> 3) & 7);
    short8 b0 = *(const short8*)&rd_s[irow * KD + ((quad ^ rsw) << 3)];
    short8 b1 = *(const short8*)&rd_s[irow * KD + (((4 + quad) ^ rsw) << 3)];
    const float diag_i = bf2f(diagg[irow]);
    f32x4 oacc[4] = {{0,0,0,0},{0,0,0,0},{0,0,0,0},{0,0,0,0}};
    const int npairs = (ib + 2) >> 1;
    unsigned short* astw = Ast + wv * 640;
    for (int jp = 0; jp < npairs; ++jp) {
      #pragma unroll
      for (int jj = 0; jj < 2; ++jj) {
        const int j = jp * 2 + jj;
        short4_t pk;
        if (j <= ib) {
          const int jrow = j * 16 + l16;
          const int jsw = (jrow & 7) ^ ((jrow >> 3) & 7);
          short8 a0 = *(const short8*)&ki_s[jrow * KD + ((quad ^ jsw) << 3)];
          short8 a1 = *(const short8*)&ki_s[jrow * KD + (((4 + quad) ^ jsw) << 3)];
          f32x4 at = {0, 0, 0, 0};
          at = __builtin_amdgcn_mfma_f32_16x16x32_bf16(a0, b0, at, 0, 0, 0);
          at = __builtin_amdgcn_mfma_f32_16x16x32_bf16(a1, b1, at, 0, 0, 0);
          #pragma unroll
          for (int reg = 0; reg < 4; ++reg) {
            const int je = j * 16 + quad * 4 + reg;
            float val = at[reg];
            if (j == ib) val = (je < irow) ? val : ((je == irow) ? diag_i : 0.f);
            pk[reg] = (short)f2bf(val);
          }
        } else {
          pk = (short4_t)0;  // guard half for even ib
        }
        *(short4_t*)&astw[l16 * 40 + jj * 16 + quad * 4] = pk;
      }
      short8 af = *(const short8*)&astw[l16 * 40 + quad * 8];
      #pragma unroll
      for (int nn = 0; nn < 4; ++nn) {
        const int vd = nn * 16 + l16;
        short8 bv = *(const short8*)&vT_s[vd * TC + (((jp * 4 + quad) ^ (vd & 7)) << 3)];
        oacc[nn] = __builtin_amdgcn_mfma_f32_16x16x32_bf16(af, bv, oacc[nn], 0, 0, 0);
      }
    }
    float* og = out + base;
    #pragma unroll
    for (int nn = 0; nn < 4; ++nn)
      #pragma unroll
      for (int reg = 0; reg < 4; ++reg)
        og[(i0 + quad * 4 + reg) * KD + nn * 16 + l16] = oacc[nn][reg];
  }
}

// ---------------------------------------------------------------------------
// K2 (fused scan + inter): block = (bh, vd-16-slab). State columns in fp32
// regs across the 16-chunk scan; per chunk: pre-update S^T bf16 -> LDS,
// out += rw @ S via MFMA (rw A-frags straight from global, coalesced),
// then state update with prefetched wkv/wse. No states array in ws.
// ---------------------------------------------------------------------------
__global__ __launch_bounds__(256)
void rwkv_scan_inter(const unsigned short* __restrict__ wkv_u16,
                     const float* __restrict__ wse_ws,
                     const float* __restrict__ st_in,
                     const unsigned short* __restrict__ rw_u16,
                     float* __restrict__ out, float* __restrict__ final_out, int N) {
  __shared__ alignas(16) unsigned short sT[16 * KD];  // [vd_l][kd] swizzled
  const int bh = blockIdx.x >> 2, vq = blockIdx.x & 3;
  const int tid = threadIdx.x;
  const int vd_l = tid & 15;
  const int kd0 = (tid >> 4) * 4;
  const size_t sbase = (size_t)bh * (KD * KD);

  float stt[4];
  #pragma unroll
  for (int j = 0; j < 4; ++j) stt[j] = st_in[sbase + (kd0 + j) * KD + vq * 16 + vd_l];

  float nwk[4], nwe[4];
  #pragma unroll
  for (int j = 0; j < 4; ++j) {
    nwk[j] = bf2f(wkv_u16[(size_t)bh * N * (KD * KD) + (kd0 + j) * KD + vq * 16 + vd_l]);
    nwe[j] = wse_ws[(size_t)bh * N * KD + kd0 + j];
  }

  const int lane = tid & 63, wv = tid >> 6, quad = lane >> 4, l16 = lane & 15;
  for (int n = 0; n < N; ++n) {
    #pragma unroll
    for (int j = 0; j < 4; ++j) {
      const int kd = kd0 + j;
      sT[vd_l * KD + ((((kd >> 3) ^ (vd_l & 7)) << 3) | (kd & 7))] = f2bf(stt[j]);
    }
    __syncthreads();

    float cwk[4], cwe[4];
    #pragma unroll
    for (int j = 0; j < 4; ++j) { cwk[j] = nwk[j]; cwe[j] = nwe[j]; }
    if (n + 1 < N) {
      const size_t b2 = (size_t)bh * N + n + 1;
      #pragma unroll
      for (int j = 0; j < 4; ++j) {
        nwk[j] = bf2f(wkv_u16[b2 * (KD * KD) + (kd0 + j) * KD + vq * 16 + vd_l]);
        nwe[j] = wse_ws[b2 * KD + kd0 + j];
      }
    }

    const unsigned short* rwg = rw_u16 + ((size_t)bh * N + n) * (TC * KD);
    float* og = out + ((size_t)bh * N + n) * (TC * KD);
    #pragma unroll
    for (int half = 0; half < 2; ++half) {
      const int mt = wv + half * 4;
      const int trow = mt * 16 + l16;
      short8 a0 = *(const short8*)&rwg[trow * KD + quad * 8];
      short8 a1 = *(const short8*)&rwg[trow * KD + 32 + quad * 8];
      short8 b0 = *(const short8*)&sT[l16 * KD + ((quad ^ (l16 & 7)) << 3)];
      short8 b1 = *(const short8*)&sT[l16 * KD + (((4 + quad) ^ (l16 & 7)) << 3)];
      f32x4 acc = {0, 0, 0, 0};
      acc = __builtin_amdgcn_mfma_f32_16x16x32_bf16(a0, b0, acc, 0, 0, 0);
      acc = __builtin_amdgcn_mfma_f32_16x16x32_bf16(a1, b1, acc, 0, 0, 0);
      #pragma unroll
      for (int reg = 0; reg < 4; ++reg) {
        const size_t oi = (size_t)(mt * 16 + quad * 4 + reg) * KD + vq * 16 + l16;
        og[oi] += acc[reg];
      }
    }

    #pragma unroll
    for (int j = 0; j < 4; ++j) stt[j] = stt[j] * cwe[j] + cwk[j];
    __syncthreads();
  }
  #pragma unroll
  for (int j = 0; j < 4; ++j)
    final_out[sbase + (kd0 + j) * KD + vq * 16 + vd_l] = stt[j];
}

// ---------------------------------------------------------------------------
// Workspace (~24.75 MB): [wkv u16: BH*N*K*K][wse f32: BH*N*K]
//                        [rw u16: BH*T*K][diag u16: BH*N*TC]
// ---------------------------------------------------------------------------
extern "C" void kernel_launch(void* const* d_in, const int* in_sizes, int n_in,
                              void* d_out, int out_size, void* d_ws, size_t ws_size,
                              hipStream_t stream) {
  const float* r = (const float*)d_in[0];
  const float* k = (const float*)d_in[1];
  const float* v = (const float*)d_in[2];
  const float* w = (const float*)d_in[3];
  const float* u = (const float*)d_in[4];
  const float* st0 = (const float*)d_in[5];
  float* out = (float*)d_out;

  const int BH = in_sizes[5] / (KD * KD);  // 64
  const int H = in_sizes[4] / KD;          // 16
  const int T = in_sizes[0] / (BH * KD);   // 2048
  const int N = T / TC;                    // 16

  unsigned short* wkv_u16 = (unsigned short*)d_ws;
  float* wse_ws = (float*)(wkv_u16 + (size_t)BH * N * KD * KD);
  unsigned short* rw_u16 = (unsigned short*)(wse_ws + (size_t)BH * N * KD);
  unsigned short* diag_u16 = rw_u16 + (size_t)BH * T * KD;
  float* final_out = out + (size_t)in_sizes[0];

  rwkv_intra_mfma<<<BH * N, 256, 0, stream>>>(r, k, v, w, u, out, wkv_u16, wse_ws,
                                              rw_u16, diag_u16, H, N);
  rwkv_scan_inter<<<BH * 4, 256, 0, stream>>>(wkv_u16, wse_ws, st0, rw_u16,
                                              out, final_out, N);
}